// Round 5
// baseline (369.509 us; speedup 1.0000x reference)
//
#include <hip/hip_runtime.h>
#include <stdint.h>
#include <math.h>

typedef unsigned int u32;
typedef unsigned long long u64;

#define B_ 16
#define N_ 200000
#define PRE 4096
#define POST 2000
#define CNT_PAD 64  // u32 stride between per-batch counters (256B apart)

// ---------------- histogram pass 1: bits [31:20] ----------------
__global__ __launch_bounds__(256) void k_hist1(const float* __restrict__ scores,
                                               u32* __restrict__ hist) {
  int b = blockIdx.y;
  __shared__ u32 h[4096];
  for (int i = threadIdx.x; i < 4096; i += blockDim.x) h[i] = 0;
  __syncthreads();
  const float* s = scores + (size_t)b * N_;
  for (int i = blockIdx.x * blockDim.x + threadIdx.x; i < N_;
       i += gridDim.x * blockDim.x) {
    u32 u = __float_as_uint(s[i]);
    atomicAdd(&h[u >> 20], 1u);
  }
  __syncthreads();
  u32* g = hist + (size_t)b * 4096;
  for (int i = threadIdx.x; i < 4096; i += blockDim.x) {
    u32 v = h[i];
    if (v) atomicAdd(&g[i], v);
  }
}

// ---------------- histogram pass 2: filter top12, bits [19:8] ----------------
__global__ __launch_bounds__(256) void k_hist2(const float* __restrict__ scores,
                                               const u32* __restrict__ pref,
                                               u32* __restrict__ hist) {
  int b = blockIdx.y;
  u32 P = pref[b];
  const float* s = scores + (size_t)b * N_;
  u32* g = hist + (size_t)b * 4096;
  for (int i = blockIdx.x * blockDim.x + threadIdx.x; i < N_;
       i += gridDim.x * blockDim.x) {
    u32 u = __float_as_uint(s[i]);
    if ((u & 0xFFF00000u) == P) atomicAdd(&g[(u >> 8) & 0xFFFu], 1u);
  }
}

// ---------------- histogram pass 3: filter top24, bits [7:0] ----------------
__global__ __launch_bounds__(256) void k_hist3(const float* __restrict__ scores,
                                               const u32* __restrict__ pref,
                                               u32* __restrict__ hist) {
  int b = blockIdx.y;
  u32 P = pref[b];
  const float* s = scores + (size_t)b * N_;
  u32* g = hist + (size_t)b * 256;
  for (int i = blockIdx.x * blockDim.x + threadIdx.x; i < N_;
       i += gridDim.x * blockDim.x) {
    u32 u = __float_as_uint(s[i]);
    if ((u & 0xFFFFFF00u) == P) atomicAdd(&g[u & 0xFFu], 1u);
  }
}

// ---------------- threshold finder (generic, 64 threads = 1 wave) -----------
__global__ __launch_bounds__(64) void k_thresh(const u32* __restrict__ hist,
                                               int nbins, int shift,
                                               u32* __restrict__ pref,
                                               u32* __restrict__ K) {
  int b = blockIdx.x;
  int t = threadIdx.x;
  const u32* h = hist + (size_t)b * nbins;
  int C = nbins >> 6;
  int base = t * C;
  u32 s = 0;
  for (int j = 0; j < C; ++j) s += h[base + j];
  u32 suf = s;  // inclusive suffix sum over lanes
#pragma unroll
  for (int off = 1; off < 64; off <<= 1) {
    u32 v = __shfl_down(suf, off);
    if (t + off < 64) suf += v;
  }
  u32 Kin = K[b];
  if (Kin == 0) Kin = PRE;  // memset-zeroed sentinel on first pass
  bool cond = (suf >= Kin) && (suf - s < Kin);
  if (cond) {
    u32 cum = suf - s;  // count strictly above my chunk
    for (int v = C - 1; v >= 0; --v) {
      u32 hv = h[base + v];
      cum += hv;
      if (cum >= Kin) {
        pref[b] |= ((u32)(base + v)) << shift;
        K[b] = Kin - (cum - hv);
        break;
      }
    }
  }
}

// ---------------- selection: >S* into sel, ==S* into eq buffer --------------
__global__ __launch_bounds__(256) void k_select(const float* __restrict__ scores,
                                                const u32* __restrict__ pref,
                                                u32* __restrict__ cnt_gt,
                                                u32* __restrict__ cnt_eq,
                                                u64* __restrict__ sel,
                                                u32* __restrict__ eqbuf) {
  int b = blockIdx.y;
  u32 S = pref[b];
  const float* s = scores + (size_t)b * N_;
  int tid = threadIdx.x;
  int lane = tid & 63, wid = tid >> 6;
  int stride = gridDim.x * blockDim.x;
  int i0 = blockIdx.x * blockDim.x + tid;

  u32 cg = 0, ce = 0;
  for (int i = i0; i < N_; i += stride) {
    u32 u = __float_as_uint(s[i]);
    cg += (u > S) ? 1u : 0u;
    ce += (u == S) ? 1u : 0u;
  }
  u32 ig = cg, ie = ce;
#pragma unroll
  for (int off = 1; off < 64; off <<= 1) {
    u32 vg = __shfl_up(ig, off);
    u32 ve = __shfl_up(ie, off);
    if (lane >= off) {
      ig += vg;
      ie += ve;
    }
  }
  __shared__ u32 wg[4], we[4], baseg, basee;
  if (lane == 63) {
    wg[wid] = ig;
    we[wid] = ie;
  }
  __syncthreads();
  if (tid == 0) {
    u32 tg = wg[0] + wg[1] + wg[2] + wg[3];
    u32 te = we[0] + we[1] + we[2] + we[3];
    baseg = tg ? atomicAdd(&cnt_gt[(size_t)b * CNT_PAD], tg) : 0u;
    basee = te ? atomicAdd(&cnt_eq[(size_t)b * CNT_PAD], te) : 0u;
  }
  __syncthreads();
  u32 woffg = 0, woffe = 0;
  for (int w = 0; w < wid; ++w) {
    woffg += wg[w];
    woffe += we[w];
  }
  u32 pg = baseg + woffg + (ig - cg);
  u32 pe = basee + woffe + (ie - ce);

  for (int i = i0; i < N_; i += stride) {
    u32 u = __float_as_uint(s[i]);
    if (u > S) {
      if (pg < PRE) sel[(size_t)b * PRE + pg] = ((u64)u << 32) | (u32)(~(u32)i);
      ++pg;
    } else if (u == S) {
      if (pe < PRE) eqbuf[(size_t)b * PRE + pe] = (u32)i;
      ++pe;
    }
  }
}

// ---------------- sort (+ tie resolve + box gather fused) -------------------
__global__ __launch_bounds__(1024) void k_sort(const u64* __restrict__ sel,
                                               const u32* __restrict__ eqbuf,
                                               const u32* __restrict__ pref,
                                               const u32* __restrict__ K,
                                               const u32* __restrict__ cnt_eq,
                                               const float4* __restrict__ boxes,
                                               float4* __restrict__ tb,
                                               float* __restrict__ sscore) {
  __shared__ u64 k[PRE];
  int b = blockIdx.x, t = threadIdx.x;
  for (int i = t; i < PRE; i += 1024) k[i] = sel[(size_t)b * PRE + i];
  __syncthreads();
  // tie fill: smallest-index Kf equals go at slots [PRE-Kf, PRE)
  {
    u32 Kf = K[b];
    u32 S = pref[b];
    u32 ne = cnt_eq[(size_t)b * CNT_PAD];
    if (ne > PRE) ne = PRE;
    u32 basep = PRE - Kf;
    const u32* eq = eqbuf + (size_t)b * PRE;
    for (u32 p = t; p < ne; p += 1024) {
      u32 my = eq[p];
      u32 rank = 0;
      for (u32 q = 0; q < ne; ++q) rank += (eq[q] < my) ? 1u : 0u;
      if (rank < Kf) k[basep + rank] = ((u64)S << 32) | (u32)(~my);
    }
  }
  __syncthreads();
  for (int kk = 2; kk <= PRE; kk <<= 1) {
    for (int j = kk >> 1; j > 0; j >>= 1) {
      for (int i = t; i < PRE; i += 1024) {
        int ixj = i ^ j;
        if (ixj > i) {
          u64 a = k[i], bv = k[ixj];
          bool up = (i & kk) == 0;
          if (up ? (a < bv) : (a > bv)) {
            k[i] = bv;
            k[ixj] = a;
          }
        }
      }
      __syncthreads();
    }
  }
  for (int i = t; i < PRE; i += 1024) {
    u64 key = k[i];
    u32 idx = ~(u32)key;
    sscore[(size_t)b * PRE + i] = __uint_as_float((u32)(key >> 32));
    tb[(size_t)b * PRE + i] = boxes[(size_t)b * N_ + idx];
  }
}

// ---------------- NMS pairwise mask: upper-triangle 64x64 tiles only --------
__global__ __launch_bounds__(64) void k_mask(const float4* __restrict__ tb,
                                             u64* __restrict__ mask) {
  int b = blockIdx.y;
  int tri = blockIdx.x;  // 0..2079 -> (rb, cb) with rb <= cb < 64
  double disc = 16641.0 - 8.0 * (double)tri;  // 129^2 - 8*tri
  int rb = (int)((129.0 - sqrt(disc)) * 0.5);
#define OFFS(r) ((r)*64 - ((r) * ((r)-1)) / 2)
  while (rb > 0 && OFFS(rb) > tri) --rb;
  while (rb < 63 && OFFS(rb + 1) <= tri) ++rb;
  int cb = rb + (tri - OFFS(rb));
#undef OFFS
  int t = threadIdx.x;
  __shared__ float4 cbox[64];
  __shared__ float carea[64];
  float4 cj = tb[(size_t)b * PRE + cb * 64 + t];
  cbox[t] = cj;
  carea[t] = (cj.z - cj.x) * (cj.w - cj.y);
  __syncthreads();
  int i = rb * 64 + t;
  float4 bi = tb[(size_t)b * PRE + i];
  float bar = (bi.z - bi.x) * (bi.w - bi.y);
  // exact equivalence to rnd32(inter/denom) > 0.7f (denom>0):
  //   suppress <=> (double)inter >= MD * (double)denom
  const double MD = (double)0.7f + 0x1.0p-25;  // midpoint; tie rounds up (even)
  u64 validm = (cb > rb) ? ~0ull : ((t == 63) ? 0ull : (~0ull << (t + 1)));
  u64 m = 0;
#pragma unroll 8
  for (int j = 0; j < 64; ++j) {
    float4 c = cbox[j];
    float iy1 = fmaxf(bi.x, c.x);
    float ix1 = fmaxf(bi.y, c.y);
    float iy2 = fminf(bi.z, c.z);
    float ix2 = fminf(bi.w, c.w);
    float inter = fmaxf(iy2 - iy1, 0.0f) * fmaxf(ix2 - ix1, 0.0f);
    float denom = bar + carea[j] - inter + 1e-9f;  // ((bar+ca)-inter)+1e-9
    double di = (double)inter, dd = (double)denom;
    bool sup = (dd > 0.0) ? (di >= MD * dd) : (dd == 0.0 ? (di > 0.0) : false);
    if (sup) m |= (1ull << j);
  }
  m &= validm;
  mask[((size_t)b * PRE + i) * 64 + cb] = m;
}

// ---------------- greedy reduce + output write ------------------------------
// Producer/consumer wave split: waves 1..7 prefetch 16-row quarter-chunks of
// the mask into a double-buffered LDS ring; wave 0 runs the serial evolve out
// of LDS. One barrier per round; early-exit via LDS flag.
#define WAVES 8
#define PROD (WAVES - 1)
#define QROWS 16
#define NQ (PRE / QROWS)                 // 256 quarters
#define ROUNDS ((NQ + PROD - 1) / PROD)  // 37

__global__ __launch_bounds__(512, 1) void k_reduce(const u64* __restrict__ mask,
                                                   const float4* __restrict__ tb,
                                                   const float* __restrict__ sscore,
                                                   float* __restrict__ out) {
  int b = blockIdx.x;
  int tid = threadIdx.x;
  int w = tid >> 6, t = tid & 63;
  __shared__ u64 sbuf[2 * PROD * QROWS * 64];  // 112 KiB ring
  __shared__ u64 skeep[64];
  __shared__ u32 sbase[64];
  __shared__ int sdone, scnt;

  const u64* mb = mask + ((size_t)b * PRE) * 64;
  u64 remv = 0;   // (wave0) suppression bits for columns [64t,64t+64)
  u64 keepm = 0;  // (wave0) keep bits for rows [64t,64t+64)
  int cnt = 0;

#define LOADQ(buf_, qi_)                                                    \
  do {                                                                      \
    int qi__ = (qi_);                                                       \
    if (qi__ < NQ) {                                                        \
      int row0_ = qi__ * QROWS;                                             \
      int rb_ = row0_ >> 6;                                                 \
      u64* dst_ = &sbuf[((size_t)(buf_)*PROD + (w - 1)) * (QROWS * 64)];    \
      if (t >= rb_) {                                                       \
        u64 tmp_[QROWS];                                                    \
        _Pragma("unroll") for (int r_ = 0; r_ < QROWS; ++r_) tmp_[r_] =     \
            mb[(size_t)(row0_ + r_) * 64 + t];                              \
        _Pragma("unroll") for (int r_ = 0; r_ < QROWS; ++r_)                \
            dst_[r_ * 64 + t] = tmp_[r_];                                   \
      } else {                                                              \
        _Pragma("unroll") for (int r_ = 0; r_ < QROWS; ++r_)                \
            dst_[r_ * 64 + t] = 0ull;                                       \
      }                                                                     \
    }                                                                       \
  } while (0)

#define PROCQ(buf_, s_, qi_)                                                \
  do {                                                                      \
    int row0_ = (qi_)*QROWS;                                                \
    int rb_ = row0_ >> 6;                                                   \
    int bb_ = row0_ & 63;                                                   \
    const u64* src_ = &sbuf[((size_t)(buf_)*PROD + (s_)) * (QROWS * 64)];   \
    u64 wb_[QROWS];                                                         \
    _Pragma("unroll") for (int r_ = 0; r_ < QROWS; ++r_) wb_[r_] =          \
        src_[r_ * 64 + t];                                                  \
    u64 rm_ = remv, kb_ = 0;                                                \
    _Pragma("unroll") for (int r_ = 0; r_ < QROWS; ++r_) {                  \
      u64 bit_ = 1ull << (bb_ + r_);                                        \
      if ((rm_ & bit_) == 0ull) {                                           \
        kb_ |= bit_;                                                        \
        rm_ |= wb_[r_];                                                     \
      }                                                                     \
    }                                                                       \
    kb_ = (u64)__shfl((long long)kb_, rb_);                                 \
    _Pragma("unroll") for (int r_ = 0; r_ < QROWS; ++r_) remv |=            \
        ((kb_ >> (bb_ + r_)) & 1ull) ? wb_[r_] : 0ull;                      \
    if (t == rb_) keepm |= kb_;                                             \
    cnt += __popcll(kb_);                                                   \
  } while (0)

  // prologue: round 0 into buf 0
  if (w > 0) LOADQ(0, 0 * PROD + (w - 1));
  if (tid == 0) sdone = 0;
  __syncthreads();

  for (int r = 0; r < ROUNDS; ++r) {
    if (w > 0) {
      LOADQ((r + 1) & 1, (r + 1) * PROD + (w - 1));
    } else if (w == 0 && t < 64) {
      int fin = 0;
      for (int s = 0; s < PROD; ++s) {
        int qi = r * PROD + s;
        if (qi >= NQ) {
          fin = 1;
          break;
        }
        PROCQ(r & 1, s, qi);
        if (cnt >= POST) {
          fin = 1;
          break;
        }
      }
      if (r == ROUNDS - 1) fin = 1;
      if (fin && t == 0) sdone = 1;
    }
    __syncthreads();
    if (sdone) break;
  }
#undef LOADQ
#undef PROCQ

  // epilogue: publish keep bits + prefix, then all 512 threads write output
  if (w == 0) {
    skeep[t] = keepm;
    int nk = __popcll(keepm);
    int inc = nk;
#pragma unroll
    for (int off = 1; off < 64; off <<= 1) {
      int v = __shfl_up(inc, off);
      if (t >= off) inc += v;
    }
    sbase[t] = (u32)(inc - nk);
    if (t == 0) scnt = cnt < POST ? cnt : POST;
  }
  __syncthreads();
  int ntot = scnt;

  const float4* tbb = tb + (size_t)b * PRE;
  const float* ssb = sscore + (size_t)b * PRE;
  float4* outb = (float4*)out + (size_t)b * POST;
  float* outs = out + (size_t)B_ * POST * 4 + (size_t)b * POST;

  for (int i = tid; i < PRE; i += 512) {
    int wi = i >> 6, bi = i & 63;
    u64 km = skeep[wi];
    if ((km >> bi) & 1ull) {
      int rr = (int)sbase[wi] + __popcll(km & ((1ull << bi) - 1ull));
      if (rr < POST) {
        float4 v = tbb[i];
        float4 bx;
        bx.x = fminf(fmaxf(v.x, 0.f), 1.f);
        bx.y = fminf(fmaxf(v.y, 0.f), 1.f);
        bx.z = fminf(fmaxf(v.z, 0.f), 1.f);
        bx.w = fminf(fmaxf(v.w, 0.f), 1.f);
        outb[rr] = bx;
        outs[rr] = ssb[i];
      }
    }
  }
  for (int s2 = ntot + tid; s2 < POST; s2 += 512) {
    outb[s2] = make_float4(0.f, 0.f, 0.f, 0.f);
    outs[s2] = 0.f;
  }
}

extern "C" void kernel_launch(void* const* d_in, const int* in_sizes, int n_in,
                              void* d_out, int out_size, void* d_ws,
                              size_t ws_size, hipStream_t stream) {
  const float* boxes = (const float*)d_in[0];   // [16,200000,4]
  const float* scores = (const float*)d_in[1];  // [16,200000,1]
  float* out = (float*)d_out;

  char* ws = (char*)d_ws;
  size_t off = 0;
  auto alloc = [&](size_t bytes) {
    size_t o = off;
    off = (off + bytes + 255) & ~(size_t)255;
    return o;
  };
  // zero-initialized region first (one memset)
  size_t o_hist1 = alloc((size_t)B_ * 4096 * 4);
  size_t o_hist2 = alloc((size_t)B_ * 4096 * 4);
  size_t o_hist3 = alloc((size_t)B_ * 256 * 4);
  size_t o_pref = alloc(B_ * 4);
  size_t o_K = alloc(B_ * 4);
  size_t o_cgt = alloc((size_t)B_ * CNT_PAD * 4);
  size_t o_ceq = alloc((size_t)B_ * CNT_PAD * 4);
  size_t zbytes = off;
  // non-zeroed scratch
  size_t o_sel = alloc((size_t)B_ * PRE * 8);
  size_t o_eq = alloc((size_t)B_ * PRE * 4);
  size_t o_sscore = alloc((size_t)B_ * PRE * 4);
  size_t o_tb = alloc((size_t)B_ * PRE * 16);
  size_t o_mask = alloc((size_t)B_ * PRE * 64 * 8);
  if (off > ws_size) return;  // workspace too small -> visible failure

  u32* hist1 = (u32*)(ws + o_hist1);
  u32* hist2 = (u32*)(ws + o_hist2);
  u32* hist3 = (u32*)(ws + o_hist3);
  u32* pref = (u32*)(ws + o_pref);
  u32* K = (u32*)(ws + o_K);
  u32* cgt = (u32*)(ws + o_cgt);
  u32* ceq = (u32*)(ws + o_ceq);
  u64* sel = (u64*)(ws + o_sel);
  u32* eqbuf = (u32*)(ws + o_eq);
  float* sscore = (float*)(ws + o_sscore);
  float4* tb = (float4*)(ws + o_tb);
  u64* mask = (u64*)(ws + o_mask);

  hipMemsetAsync(d_ws, 0, zbytes, stream);

  dim3 scanGrid(128, B_);
  k_hist1<<<scanGrid, 256, 0, stream>>>(scores, hist1);
  k_thresh<<<B_, 64, 0, stream>>>(hist1, 4096, 20, pref, K);
  k_hist2<<<scanGrid, 256, 0, stream>>>(scores, pref, hist2);
  k_thresh<<<B_, 64, 0, stream>>>(hist2, 4096, 8, pref, K);
  k_hist3<<<scanGrid, 256, 0, stream>>>(scores, pref, hist3);
  k_thresh<<<B_, 64, 0, stream>>>(hist3, 256, 0, pref, K);
  k_select<<<scanGrid, 256, 0, stream>>>(scores, pref, cgt, ceq, sel, eqbuf);
  k_sort<<<B_, 1024, 0, stream>>>(sel, eqbuf, pref, K, ceq,
                                  (const float4*)boxes, tb, sscore);
  k_mask<<<dim3(2080, B_), 64, 0, stream>>>(tb, mask);
  k_reduce<<<B_, 512, 0, stream>>>(mask, tb, sscore, out);
}

// Round 6
// 350.093 us; speedup vs baseline: 1.0555x; 1.0555x over previous
//
#include <hip/hip_runtime.h>
#include <stdint.h>
#include <math.h>

typedef unsigned int u32;
typedef unsigned long long u64;

#define B_ 16
#define N_ 200000
#define PRE 4096
#define POST 2000
#define CNT_PAD 64  // u32 stride between per-batch counters (256B apart)

// ---------------- histogram pass 1: bits [31:20] ----------------
__global__ __launch_bounds__(256) void k_hist1(const float* __restrict__ scores,
                                               u32* __restrict__ hist) {
  int b = blockIdx.y;
  __shared__ u32 h[4096];
  for (int i = threadIdx.x; i < 4096; i += blockDim.x) h[i] = 0;
  __syncthreads();
  const float* s = scores + (size_t)b * N_;
  for (int i = blockIdx.x * blockDim.x + threadIdx.x; i < N_;
       i += gridDim.x * blockDim.x) {
    u32 u = __float_as_uint(s[i]);
    atomicAdd(&h[u >> 20], 1u);
  }
  __syncthreads();
  u32* g = hist + (size_t)b * 4096;
  for (int i = threadIdx.x; i < 4096; i += blockDim.x) {
    u32 v = h[i];
    if (v) atomicAdd(&g[i], v);
  }
}

// ---------------- histogram pass 2: filter top12, bits [19:8] ----------------
__global__ __launch_bounds__(256) void k_hist2(const float* __restrict__ scores,
                                               const u32* __restrict__ pref,
                                               u32* __restrict__ hist) {
  int b = blockIdx.y;
  u32 P = pref[b];
  const float* s = scores + (size_t)b * N_;
  u32* g = hist + (size_t)b * 4096;
  for (int i = blockIdx.x * blockDim.x + threadIdx.x; i < N_;
       i += gridDim.x * blockDim.x) {
    u32 u = __float_as_uint(s[i]);
    if ((u & 0xFFF00000u) == P) atomicAdd(&g[(u >> 8) & 0xFFFu], 1u);
  }
}

// ---------------- histogram pass 3: filter top24, bits [7:0] ----------------
__global__ __launch_bounds__(256) void k_hist3(const float* __restrict__ scores,
                                               const u32* __restrict__ pref,
                                               u32* __restrict__ hist) {
  int b = blockIdx.y;
  u32 P = pref[b];
  const float* s = scores + (size_t)b * N_;
  u32* g = hist + (size_t)b * 256;
  for (int i = blockIdx.x * blockDim.x + threadIdx.x; i < N_;
       i += gridDim.x * blockDim.x) {
    u32 u = __float_as_uint(s[i]);
    if ((u & 0xFFFFFF00u) == P) atomicAdd(&g[u & 0xFFu], 1u);
  }
}

// ---------------- threshold finder (generic, 64 threads = 1 wave) -----------
__global__ __launch_bounds__(64) void k_thresh(const u32* __restrict__ hist,
                                               int nbins, int shift,
                                               u32* __restrict__ pref,
                                               u32* __restrict__ K) {
  int b = blockIdx.x;
  int t = threadIdx.x;
  const u32* h = hist + (size_t)b * nbins;
  int C = nbins >> 6;
  int base = t * C;
  u32 s = 0;
  for (int j = 0; j < C; ++j) s += h[base + j];
  u32 suf = s;  // inclusive suffix sum over lanes
#pragma unroll
  for (int off = 1; off < 64; off <<= 1) {
    u32 v = __shfl_down(suf, off);
    if (t + off < 64) suf += v;
  }
  u32 Kin = K[b];
  if (Kin == 0) Kin = PRE;  // memset-zeroed sentinel on first pass
  bool cond = (suf >= Kin) && (suf - s < Kin);
  if (cond) {
    u32 cum = suf - s;  // count strictly above my chunk
    for (int v = C - 1; v >= 0; --v) {
      u32 hv = h[base + v];
      cum += hv;
      if (cum >= Kin) {
        pref[b] |= ((u32)(base + v)) << shift;
        K[b] = Kin - (cum - hv);
        break;
      }
    }
  }
}

// ---------------- selection: >S* into sel, ==S* into eq buffer --------------
__global__ __launch_bounds__(256) void k_select(const float* __restrict__ scores,
                                                const u32* __restrict__ pref,
                                                u32* __restrict__ cnt_gt,
                                                u32* __restrict__ cnt_eq,
                                                u64* __restrict__ sel,
                                                u32* __restrict__ eqbuf) {
  int b = blockIdx.y;
  u32 S = pref[b];
  const float* s = scores + (size_t)b * N_;
  int tid = threadIdx.x;
  int lane = tid & 63, wid = tid >> 6;
  int stride = gridDim.x * blockDim.x;
  int i0 = blockIdx.x * blockDim.x + tid;

  u32 cg = 0, ce = 0;
  for (int i = i0; i < N_; i += stride) {
    u32 u = __float_as_uint(s[i]);
    cg += (u > S) ? 1u : 0u;
    ce += (u == S) ? 1u : 0u;
  }
  u32 ig = cg, ie = ce;
#pragma unroll
  for (int off = 1; off < 64; off <<= 1) {
    u32 vg = __shfl_up(ig, off);
    u32 ve = __shfl_up(ie, off);
    if (lane >= off) {
      ig += vg;
      ie += ve;
    }
  }
  __shared__ u32 wg[4], we[4], baseg, basee;
  if (lane == 63) {
    wg[wid] = ig;
    we[wid] = ie;
  }
  __syncthreads();
  if (tid == 0) {
    u32 tg = wg[0] + wg[1] + wg[2] + wg[3];
    u32 te = we[0] + we[1] + we[2] + we[3];
    baseg = tg ? atomicAdd(&cnt_gt[(size_t)b * CNT_PAD], tg) : 0u;
    basee = te ? atomicAdd(&cnt_eq[(size_t)b * CNT_PAD], te) : 0u;
  }
  __syncthreads();
  u32 woffg = 0, woffe = 0;
  for (int w = 0; w < wid; ++w) {
    woffg += wg[w];
    woffe += we[w];
  }
  u32 pg = baseg + woffg + (ig - cg);
  u32 pe = basee + woffe + (ie - ce);

  for (int i = i0; i < N_; i += stride) {
    u32 u = __float_as_uint(s[i]);
    if (u > S) {
      if (pg < PRE) sel[(size_t)b * PRE + pg] = ((u64)u << 32) | (u32)(~(u32)i);
      ++pg;
    } else if (u == S) {
      if (pe < PRE) eqbuf[(size_t)b * PRE + pe] = (u32)i;
      ++pe;
    }
  }
}

// ---------------- sort (+ tie resolve + box gather fused) -------------------
__global__ __launch_bounds__(1024) void k_sort(const u64* __restrict__ sel,
                                               const u32* __restrict__ eqbuf,
                                               const u32* __restrict__ pref,
                                               const u32* __restrict__ K,
                                               const u32* __restrict__ cnt_eq,
                                               const float4* __restrict__ boxes,
                                               float4* __restrict__ tb,
                                               float* __restrict__ sscore) {
  __shared__ u64 k[PRE];
  int b = blockIdx.x, t = threadIdx.x;
  for (int i = t; i < PRE; i += 1024) k[i] = sel[(size_t)b * PRE + i];
  __syncthreads();
  // tie fill: smallest-index Kf equals go at slots [PRE-Kf, PRE)
  {
    u32 Kf = K[b];
    u32 S = pref[b];
    u32 ne = cnt_eq[(size_t)b * CNT_PAD];
    if (ne > PRE) ne = PRE;
    u32 basep = PRE - Kf;
    const u32* eq = eqbuf + (size_t)b * PRE;
    for (u32 p = t; p < ne; p += 1024) {
      u32 my = eq[p];
      u32 rank = 0;
      for (u32 q = 0; q < ne; ++q) rank += (eq[q] < my) ? 1u : 0u;
      if (rank < Kf) k[basep + rank] = ((u64)S << 32) | (u32)(~my);
    }
  }
  __syncthreads();
  for (int kk = 2; kk <= PRE; kk <<= 1) {
    for (int j = kk >> 1; j > 0; j >>= 1) {
      for (int i = t; i < PRE; i += 1024) {
        int ixj = i ^ j;
        if (ixj > i) {
          u64 a = k[i], bv = k[ixj];
          bool up = (i & kk) == 0;
          if (up ? (a < bv) : (a > bv)) {
            k[i] = bv;
            k[ixj] = a;
          }
        }
      }
      __syncthreads();
    }
  }
  for (int i = t; i < PRE; i += 1024) {
    u64 key = k[i];
    u32 idx = ~(u32)key;
    sscore[(size_t)b * PRE + i] = __uint_as_float((u32)(key >> 32));
    tb[(size_t)b * PRE + i] = boxes[(size_t)b * N_ + idx];
  }
}

// ---------------- NMS pairwise mask: upper-triangle 64x64 tiles only --------
__global__ __launch_bounds__(64) void k_mask(const float4* __restrict__ tb,
                                             u64* __restrict__ mask) {
  int b = blockIdx.y;
  int tri = blockIdx.x;  // 0..2079 -> (rb, cb) with rb <= cb < 64
  double disc = 16641.0 - 8.0 * (double)tri;  // 129^2 - 8*tri
  int rb = (int)((129.0 - sqrt(disc)) * 0.5);
#define OFFS(r) ((r)*64 - ((r) * ((r)-1)) / 2)
  while (rb > 0 && OFFS(rb) > tri) --rb;
  while (rb < 63 && OFFS(rb + 1) <= tri) ++rb;
  int cb = rb + (tri - OFFS(rb));
#undef OFFS
  int t = threadIdx.x;
  __shared__ float4 cbox[64];
  __shared__ float carea[64];
  float4 cj = tb[(size_t)b * PRE + cb * 64 + t];
  cbox[t] = cj;
  carea[t] = (cj.z - cj.x) * (cj.w - cj.y);
  __syncthreads();
  int i = rb * 64 + t;
  float4 bi = tb[(size_t)b * PRE + i];
  float bar = (bi.z - bi.x) * (bi.w - bi.y);
  // exact equivalence to rnd32(inter/denom) > 0.7f (denom>0):
  //   suppress <=> (double)inter >= MD * (double)denom
  const double MD = (double)0.7f + 0x1.0p-25;  // midpoint; tie rounds up (even)
  u64 validm = (cb > rb) ? ~0ull : ((t == 63) ? 0ull : (~0ull << (t + 1)));
  u64 m = 0;
#pragma unroll 8
  for (int j = 0; j < 64; ++j) {
    float4 c = cbox[j];
    float iy1 = fmaxf(bi.x, c.x);
    float ix1 = fmaxf(bi.y, c.y);
    float iy2 = fminf(bi.z, c.z);
    float ix2 = fminf(bi.w, c.w);
    float inter = fmaxf(iy2 - iy1, 0.0f) * fmaxf(ix2 - ix1, 0.0f);
    float denom = bar + carea[j] - inter + 1e-9f;  // ((bar+ca)-inter)+1e-9
    double di = (double)inter, dd = (double)denom;
    bool sup = (dd > 0.0) ? (di >= MD * dd) : (dd == 0.0 ? (di > 0.0) : false);
    if (sup) m |= (1ull << j);
  }
  m &= validm;
  mask[((size_t)b * PRE + i) * 64 + cb] = m;
}

// ---------------- greedy reduce + output write ------------------------------
// Producer waves 1..7: global_load_lds (16B) direct into double-buffered LDS
// ring (no VGPR roundtrip, no per-element waits). Wave 0: per 16-row quarter,
// one asm-batched block of 16 ds_read_b64 + single lgkmcnt(0) + sched_barrier
// (rule #18), evolve, readlane broadcast (VALU, not LDS), scalar-gated apply.
#define WAVES 8
#define PROD (WAVES - 1)
#define QROWS 16
#define NQ (PRE / QROWS)                 // 256 quarters
#define ROUNDS ((NQ + PROD - 1) / PROD)  // 37

__global__ __launch_bounds__(512, 1) void k_reduce(const u64* __restrict__ mask,
                                                   const float4* __restrict__ tb,
                                                   const float* __restrict__ sscore,
                                                   float* __restrict__ out) {
  int b = blockIdx.x;
  int tid = threadIdx.x;
  int w = tid >> 6, t = tid & 63;
  __shared__ u64 sbuf[2 * PROD * QROWS * 64];  // 112 KiB ring
  __shared__ u64 skeep[64];
  __shared__ u32 sbase[64];
  __shared__ int sdone, scnt;

  const u64* mb = mask + ((size_t)b * PRE) * 64;
  u64 remv = 0;   // (wave0) suppression bits for columns [64t,64t+64)
  u64 keepm = 0;  // (wave0) keep bits for rows [64t,64t+64)
  int cnt = 0;
  u32 sbufB = (u32)(uintptr_t)&sbuf[0];

  // producer: load quarter qi into ring buffer half `buf_`
#define LOADQ(buf_, qi_)                                                     \
  do {                                                                       \
    int qi__ = (qi_);                                                        \
    if (qi__ < NQ) {                                                         \
      const char* gsrc_ = (const char*)(mb + (size_t)qi__ * QROWS * 64);     \
      char* ldst_ =                                                          \
          (char*)sbuf + (size_t)(((buf_)*PROD + (w - 1)) * (QROWS * 64)) * 8;\
      _Pragma("unroll") for (int g_ = 0; g_ < 8; ++g_) {                     \
        __builtin_amdgcn_global_load_lds(                                    \
            (const __attribute__((address_space(1))) void*)(gsrc_ +          \
                                                            g_ * 1024 +     \
                                                            t * 16),         \
            (__attribute__((address_space(3))) void*)(ldst_ + g_ * 1024),    \
            16, 0, 0);                                                       \
      }                                                                      \
    }                                                                        \
  } while (0)

  // prologue: round 0 into buf 0
  if (w > 0) LOADQ(0, (w - 1));
  if (tid == 0) sdone = 0;
  __syncthreads();

  for (int r = 0; r < ROUNDS; ++r) {
    if (w > 0) {
      LOADQ((r + 1) & 1, (r + 1) * PROD + (w - 1));
    } else {
      int fin = 0;
      for (int s = 0; s < PROD; ++s) {
        int qi = r * PROD + s;
        if (qi >= NQ) {
          fin = 1;
          break;
        }
        int rb_ = qi >> 2;        // (qi*16)>>6
        int bb_ = (qi & 3) * 16;  // (qi*16)&63
        u32 lb = sbufB +
                 (u32)((((r & 1) * PROD + s) * (QROWS * 64)) * 8) +
                 (u32)t * 8u;
        u64 w0, w1, w2, w3, w4, w5, w6, w7, w8, w9, w10, w11, w12, w13, w14,
            w15;
        asm volatile(
            "ds_read_b64 %0, %16 offset:0\n\t"
            "ds_read_b64 %1, %16 offset:512\n\t"
            "ds_read_b64 %2, %16 offset:1024\n\t"
            "ds_read_b64 %3, %16 offset:1536\n\t"
            "ds_read_b64 %4, %16 offset:2048\n\t"
            "ds_read_b64 %5, %16 offset:2560\n\t"
            "ds_read_b64 %6, %16 offset:3072\n\t"
            "ds_read_b64 %7, %16 offset:3584\n\t"
            "ds_read_b64 %8, %16 offset:4096\n\t"
            "ds_read_b64 %9, %16 offset:4608\n\t"
            "ds_read_b64 %10, %16 offset:5120\n\t"
            "ds_read_b64 %11, %16 offset:5632\n\t"
            "ds_read_b64 %12, %16 offset:6144\n\t"
            "ds_read_b64 %13, %16 offset:6656\n\t"
            "ds_read_b64 %14, %16 offset:7168\n\t"
            "ds_read_b64 %15, %16 offset:7680\n\t"
            : "=&v"(w0), "=&v"(w1), "=&v"(w2), "=&v"(w3), "=&v"(w4),
              "=&v"(w5), "=&v"(w6), "=&v"(w7), "=&v"(w8), "=&v"(w9),
              "=&v"(w10), "=&v"(w11), "=&v"(w12), "=&v"(w13), "=&v"(w14),
              "=&v"(w15)
            : "v"(lb));
        asm volatile("s_waitcnt lgkmcnt(0)" ::: "memory");
        __builtin_amdgcn_sched_barrier(0);

        u64 rm = remv, kbv = 0;
        u64 bit = 1ull << bb_;
#define EVR(i)                         \
  {                                    \
    if (!(rm & (bit << i))) {          \
      kbv |= (bit << i);               \
      rm |= w##i;                      \
    }                                  \
  }
        EVR(0) EVR(1) EVR(2) EVR(3) EVR(4) EVR(5) EVR(6) EVR(7) EVR(8)
        EVR(9) EVR(10) EVR(11) EVR(12) EVR(13) EVR(14) EVR(15)
#undef EVR
        u32 klo = __builtin_amdgcn_readlane((u32)kbv, rb_);
        u32 khi = __builtin_amdgcn_readlane((u32)(kbv >> 32), rb_);
        u64 kb = ((u64)khi << 32) | klo;
        u32 kq = (u32)(kb >> bb_) & 0xFFFFu;
#define APR(i)                         \
  {                                    \
    if ((kq >> i) & 1u) remv |= w##i;  \
  }
        APR(0) APR(1) APR(2) APR(3) APR(4) APR(5) APR(6) APR(7) APR(8)
        APR(9) APR(10) APR(11) APR(12) APR(13) APR(14) APR(15)
#undef APR
        if (t == rb_) keepm |= kb;
        cnt += __popc(kq);
        if (cnt >= POST) {
          fin = 1;
          break;
        }
      }
      if (r == ROUNDS - 1) fin = 1;
      if (fin && t == 0) sdone = 1;
    }
    __syncthreads();
    if (sdone) break;
  }
#undef LOADQ

  // epilogue: publish keep bits + prefix, then all 512 threads write output
  if (w == 0) {
    skeep[t] = keepm;
    int nk = __popcll(keepm);
    int inc = nk;
#pragma unroll
    for (int off = 1; off < 64; off <<= 1) {
      int v = __shfl_up(inc, off);
      if (t >= off) inc += v;
    }
    sbase[t] = (u32)(inc - nk);
    if (t == 0) scnt = cnt < POST ? cnt : POST;
  }
  __syncthreads();
  int ntot = scnt;

  const float4* tbb = tb + (size_t)b * PRE;
  const float* ssb = sscore + (size_t)b * PRE;
  float4* outb = (float4*)out + (size_t)b * POST;
  float* outs = out + (size_t)B_ * POST * 4 + (size_t)b * POST;

  for (int i = tid; i < PRE; i += 512) {
    int wi = i >> 6, bi = i & 63;
    u64 km = skeep[wi];
    if ((km >> bi) & 1ull) {
      int rr = (int)sbase[wi] + __popcll(km & ((1ull << bi) - 1ull));
      if (rr < POST) {
        float4 v = tbb[i];
        float4 bx;
        bx.x = fminf(fmaxf(v.x, 0.f), 1.f);
        bx.y = fminf(fmaxf(v.y, 0.f), 1.f);
        bx.z = fminf(fmaxf(v.z, 0.f), 1.f);
        bx.w = fminf(fmaxf(v.w, 0.f), 1.f);
        outb[rr] = bx;
        outs[rr] = ssb[i];
      }
    }
  }
  for (int s2 = ntot + tid; s2 < POST; s2 += 512) {
    outb[s2] = make_float4(0.f, 0.f, 0.f, 0.f);
    outs[s2] = 0.f;
  }
}

extern "C" void kernel_launch(void* const* d_in, const int* in_sizes, int n_in,
                              void* d_out, int out_size, void* d_ws,
                              size_t ws_size, hipStream_t stream) {
  const float* boxes = (const float*)d_in[0];   // [16,200000,4]
  const float* scores = (const float*)d_in[1];  // [16,200000,1]
  float* out = (float*)d_out;

  char* ws = (char*)d_ws;
  size_t off = 0;
  auto alloc = [&](size_t bytes) {
    size_t o = off;
    off = (off + bytes + 255) & ~(size_t)255;
    return o;
  };
  // zero-initialized region first (one memset)
  size_t o_hist1 = alloc((size_t)B_ * 4096 * 4);
  size_t o_hist2 = alloc((size_t)B_ * 4096 * 4);
  size_t o_hist3 = alloc((size_t)B_ * 256 * 4);
  size_t o_pref = alloc(B_ * 4);
  size_t o_K = alloc(B_ * 4);
  size_t o_cgt = alloc((size_t)B_ * CNT_PAD * 4);
  size_t o_ceq = alloc((size_t)B_ * CNT_PAD * 4);
  size_t zbytes = off;
  // non-zeroed scratch
  size_t o_sel = alloc((size_t)B_ * PRE * 8);
  size_t o_eq = alloc((size_t)B_ * PRE * 4);
  size_t o_sscore = alloc((size_t)B_ * PRE * 4);
  size_t o_tb = alloc((size_t)B_ * PRE * 16);
  size_t o_mask = alloc((size_t)B_ * PRE * 64 * 8);
  if (off > ws_size) return;  // workspace too small -> visible failure

  u32* hist1 = (u32*)(ws + o_hist1);
  u32* hist2 = (u32*)(ws + o_hist2);
  u32* hist3 = (u32*)(ws + o_hist3);
  u32* pref = (u32*)(ws + o_pref);
  u32* K = (u32*)(ws + o_K);
  u32* cgt = (u32*)(ws + o_cgt);
  u32* ceq = (u32*)(ws + o_ceq);
  u64* sel = (u64*)(ws + o_sel);
  u32* eqbuf = (u32*)(ws + o_eq);
  float* sscore = (float*)(ws + o_sscore);
  float4* tb = (float4*)(ws + o_tb);
  u64* mask = (u64*)(ws + o_mask);

  hipMemsetAsync(d_ws, 0, zbytes, stream);

  dim3 scanGrid(128, B_);
  k_hist1<<<scanGrid, 256, 0, stream>>>(scores, hist1);
  k_thresh<<<B_, 64, 0, stream>>>(hist1, 4096, 20, pref, K);
  k_hist2<<<scanGrid, 256, 0, stream>>>(scores, pref, hist2);
  k_thresh<<<B_, 64, 0, stream>>>(hist2, 4096, 8, pref, K);
  k_hist3<<<scanGrid, 256, 0, stream>>>(scores, pref, hist3);
  k_thresh<<<B_, 64, 0, stream>>>(hist3, 256, 0, pref, K);
  k_select<<<scanGrid, 256, 0, stream>>>(scores, pref, cgt, ceq, sel, eqbuf);
  k_sort<<<B_, 1024, 0, stream>>>(sel, eqbuf, pref, K, ceq,
                                  (const float4*)boxes, tb, sscore);
  k_mask<<<dim3(2080, B_), 64, 0, stream>>>(tb, mask);
  k_reduce<<<B_, 512, 0, stream>>>(mask, tb, sscore, out);
}

// Round 7
// 276.066 us; speedup vs baseline: 1.3385x; 1.2681x over previous
//
#include <hip/hip_runtime.h>
#include <stdint.h>
#include <math.h>

typedef unsigned int u32;
typedef unsigned long long u64;

#define B_ 16
#define N_ 200000
#define PRE 4096
#define POST 2000
#define CNT_PAD 64  // u32 stride between per-batch counters (256B apart)

// ---------------- histogram pass 1: bits [31:20] ----------------
__global__ __launch_bounds__(256) void k_hist1(const float* __restrict__ scores,
                                               u32* __restrict__ hist) {
  int b = blockIdx.y;
  __shared__ u32 h[4096];
  for (int i = threadIdx.x; i < 4096; i += blockDim.x) h[i] = 0;
  __syncthreads();
  const float* s = scores + (size_t)b * N_;
  for (int i = blockIdx.x * blockDim.x + threadIdx.x; i < N_;
       i += gridDim.x * blockDim.x) {
    u32 u = __float_as_uint(s[i]);
    atomicAdd(&h[u >> 20], 1u);
  }
  __syncthreads();
  u32* g = hist + (size_t)b * 4096;
  for (int i = threadIdx.x; i < 4096; i += blockDim.x) {
    u32 v = h[i];
    if (v) atomicAdd(&g[i], v);
  }
}

// ---------------- histogram pass 2: filter top12, bits [19:8] ----------------
__global__ __launch_bounds__(256) void k_hist2(const float* __restrict__ scores,
                                               const u32* __restrict__ pref,
                                               u32* __restrict__ hist) {
  int b = blockIdx.y;
  u32 P = pref[b];
  const float* s = scores + (size_t)b * N_;
  u32* g = hist + (size_t)b * 4096;
  for (int i = blockIdx.x * blockDim.x + threadIdx.x; i < N_;
       i += gridDim.x * blockDim.x) {
    u32 u = __float_as_uint(s[i]);
    if ((u & 0xFFF00000u) == P) atomicAdd(&g[(u >> 8) & 0xFFFu], 1u);
  }
}

// ---------------- histogram pass 3: filter top24, bits [7:0] ----------------
__global__ __launch_bounds__(256) void k_hist3(const float* __restrict__ scores,
                                               const u32* __restrict__ pref,
                                               u32* __restrict__ hist) {
  int b = blockIdx.y;
  u32 P = pref[b];
  const float* s = scores + (size_t)b * N_;
  u32* g = hist + (size_t)b * 256;
  for (int i = blockIdx.x * blockDim.x + threadIdx.x; i < N_;
       i += gridDim.x * blockDim.x) {
    u32 u = __float_as_uint(s[i]);
    if ((u & 0xFFFFFF00u) == P) atomicAdd(&g[u & 0xFFu], 1u);
  }
}

// ---------------- threshold finder (generic, 64 threads = 1 wave) -----------
__global__ __launch_bounds__(64) void k_thresh(const u32* __restrict__ hist,
                                               int nbins, int shift,
                                               u32* __restrict__ pref,
                                               u32* __restrict__ K) {
  int b = blockIdx.x;
  int t = threadIdx.x;
  const u32* h = hist + (size_t)b * nbins;
  int C = nbins >> 6;
  int base = t * C;
  u32 s = 0;
  for (int j = 0; j < C; ++j) s += h[base + j];
  u32 suf = s;  // inclusive suffix sum over lanes
#pragma unroll
  for (int off = 1; off < 64; off <<= 1) {
    u32 v = __shfl_down(suf, off);
    if (t + off < 64) suf += v;
  }
  u32 Kin = K[b];
  if (Kin == 0) Kin = PRE;  // memset-zeroed sentinel on first pass
  bool cond = (suf >= Kin) && (suf - s < Kin);
  if (cond) {
    u32 cum = suf - s;  // count strictly above my chunk
    for (int v = C - 1; v >= 0; --v) {
      u32 hv = h[base + v];
      cum += hv;
      if (cum >= Kin) {
        pref[b] |= ((u32)(base + v)) << shift;
        K[b] = Kin - (cum - hv);
        break;
      }
    }
  }
}

// ---------------- selection: >S* into sel, ==S* into eq buffer --------------
__global__ __launch_bounds__(256) void k_select(const float* __restrict__ scores,
                                                const u32* __restrict__ pref,
                                                u32* __restrict__ cnt_gt,
                                                u32* __restrict__ cnt_eq,
                                                u64* __restrict__ sel,
                                                u32* __restrict__ eqbuf) {
  int b = blockIdx.y;
  u32 S = pref[b];
  const float* s = scores + (size_t)b * N_;
  int tid = threadIdx.x;
  int lane = tid & 63, wid = tid >> 6;
  int stride = gridDim.x * blockDim.x;
  int i0 = blockIdx.x * blockDim.x + tid;

  u32 cg = 0, ce = 0;
  for (int i = i0; i < N_; i += stride) {
    u32 u = __float_as_uint(s[i]);
    cg += (u > S) ? 1u : 0u;
    ce += (u == S) ? 1u : 0u;
  }
  u32 ig = cg, ie = ce;
#pragma unroll
  for (int off = 1; off < 64; off <<= 1) {
    u32 vg = __shfl_up(ig, off);
    u32 ve = __shfl_up(ie, off);
    if (lane >= off) {
      ig += vg;
      ie += ve;
    }
  }
  __shared__ u32 wg[4], we[4], baseg, basee;
  if (lane == 63) {
    wg[wid] = ig;
    we[wid] = ie;
  }
  __syncthreads();
  if (tid == 0) {
    u32 tg = wg[0] + wg[1] + wg[2] + wg[3];
    u32 te = we[0] + we[1] + we[2] + we[3];
    baseg = tg ? atomicAdd(&cnt_gt[(size_t)b * CNT_PAD], tg) : 0u;
    basee = te ? atomicAdd(&cnt_eq[(size_t)b * CNT_PAD], te) : 0u;
  }
  __syncthreads();
  u32 woffg = 0, woffe = 0;
  for (int w = 0; w < wid; ++w) {
    woffg += wg[w];
    woffe += we[w];
  }
  u32 pg = baseg + woffg + (ig - cg);
  u32 pe = basee + woffe + (ie - ce);

  for (int i = i0; i < N_; i += stride) {
    u32 u = __float_as_uint(s[i]);
    if (u > S) {
      if (pg < PRE) sel[(size_t)b * PRE + pg] = ((u64)u << 32) | (u32)(~(u32)i);
      ++pg;
    } else if (u == S) {
      if (pe < PRE) eqbuf[(size_t)b * PRE + pe] = (u32)i;
      ++pe;
    }
  }
}

// ---------------- tie resolve: smallest Kf indices among equals -------------
__global__ __launch_bounds__(256) void k_tie(const u32* __restrict__ pref,
                                             const u32* __restrict__ K,
                                             const u32* __restrict__ cnt_eq,
                                             const u32* __restrict__ eqbuf,
                                             u64* __restrict__ sel) {
  int b = blockIdx.x;
  u32 Kf = K[b];
  u32 ne = cnt_eq[(size_t)b * CNT_PAD];
  if (ne > PRE) ne = PRE;
  u32 S = pref[b];
  u32 basep = PRE - Kf;
  const u32* eq = eqbuf + (size_t)b * PRE;
  for (u32 p = threadIdx.x; p < ne; p += blockDim.x) {
    u32 my = eq[p];
    u32 rank = 0;
    for (u32 q = 0; q < ne; ++q) rank += (eq[q] < my) ? 1u : 0u;
    if (rank < Kf)
      sel[(size_t)b * PRE + basep + rank] = ((u64)S << 32) | (u32)(~my);
  }
}

// ---------------- rank-by-count sort (+ box gather fused) -------------------
// Keys are unique (index in low bits) -> rank is a permutation of [0,PRE).
__global__ __launch_bounds__(256) void k_rank(const u64* __restrict__ sel,
                                              const float4* __restrict__ boxes,
                                              float4* __restrict__ tb,
                                              float* __restrict__ sscore) {
  int b = blockIdx.y;
  int tid = threadIdx.x;
  __shared__ u64 cols[512];
  const u64* sb = sel + (size_t)b * PRE;
  int row = blockIdx.x * 256 + tid;
  u64 key = sb[row];
  int rank = 0;
  for (int c0 = 0; c0 < PRE; c0 += 512) {
    cols[tid] = sb[c0 + tid];
    cols[tid + 256] = sb[c0 + tid + 256];
    __syncthreads();
#pragma unroll 8
    for (int j = 0; j < 512; ++j) rank += (cols[j] > key) ? 1 : 0;
    __syncthreads();
  }
  u32 idx = ~(u32)key;
  sscore[(size_t)b * PRE + rank] = __uint_as_float((u32)(key >> 32));
  tb[(size_t)b * PRE + rank] = boxes[(size_t)b * N_ + idx];
}

// ---------------- NMS pairwise mask: upper-triangle 64x64 tiles only --------
__global__ __launch_bounds__(64) void k_mask(const float4* __restrict__ tb,
                                             u64* __restrict__ mask) {
  int b = blockIdx.y;
  int tri = blockIdx.x;  // 0..2079 -> (rb, cb) with rb <= cb < 64
  double disc = 16641.0 - 8.0 * (double)tri;  // 129^2 - 8*tri
  int rb = (int)((129.0 - sqrt(disc)) * 0.5);
#define OFFS(r) ((r)*64 - ((r) * ((r)-1)) / 2)
  while (rb > 0 && OFFS(rb) > tri) --rb;
  while (rb < 63 && OFFS(rb + 1) <= tri) ++rb;
  int cb = rb + (tri - OFFS(rb));
#undef OFFS
  int t = threadIdx.x;
  __shared__ float4 cbox[64];
  __shared__ float carea[64];
  float4 cj = tb[(size_t)b * PRE + cb * 64 + t];
  cbox[t] = cj;
  carea[t] = (cj.z - cj.x) * (cj.w - cj.y);
  __syncthreads();
  int i = rb * 64 + t;
  float4 bi = tb[(size_t)b * PRE + i];
  float bar = (bi.z - bi.x) * (bi.w - bi.y);
  // exact equivalence to rnd32(inter/denom) > 0.7f (denom>0):
  //   suppress <=> (double)inter >= MD * (double)denom
  const double MD = (double)0.7f + 0x1.0p-25;  // midpoint; tie rounds up (even)
  u64 validm = (cb > rb) ? ~0ull : ((t == 63) ? 0ull : (~0ull << (t + 1)));
  u64 m = 0;
#pragma unroll 8
  for (int j = 0; j < 64; ++j) {
    float4 c = cbox[j];
    float iy1 = fmaxf(bi.x, c.x);
    float ix1 = fmaxf(bi.y, c.y);
    float iy2 = fminf(bi.z, c.z);
    float ix2 = fminf(bi.w, c.w);
    float inter = fmaxf(iy2 - iy1, 0.0f) * fmaxf(ix2 - ix1, 0.0f);
    float denom = bar + carea[j] - inter + 1e-9f;  // ((bar+ca)-inter)+1e-9
    double di = (double)inter, dd = (double)denom;
    bool sup = (dd > 0.0) ? (di >= MD * dd) : (dd == 0.0 ? (di > 0.0) : false);
    if (sup) m |= (1ull << j);
  }
  m &= validm;
  mask[((size_t)b * PRE + i) * 64 + cb] = m;
}

// ---------------- greedy reduce + output write ------------------------------
// 1 consumer wave + 8 producer waves. Producers: global_load_lds 16-row
// quarters into a 128KB double-buffered LDS ring. Consumer: 32-row half-blocks;
// serial evolve = 3 dependent 32-bit VALU per row (bfe_i32 / and / bfi) on an
// alive-mask; kq = final alive bits (no per-step accumulation); ONE readlane
// per 32 rows; uniform-gated tree apply. Lower-triangle garbage words only
// pollute remv words of already-processed blocks (invariant, harmless).
#define WAVES 9
#define PROD 8
#define QROWS 16
#define NQ (PRE / QROWS)  // 256
#define RND (NQ / PROD)   // 32 rounds x 128 rows

#define EVS(bit, qn)                                  \
  "v_bfe_i32 %[e], %[a], " #bit ", 1\n\t"             \
  "v_and_b32 %[e], %[" qn "], %[e]\n\t"               \
  "v_bfi_b32 %[a], %[e], 0, %[a]\n\t"

#define EVBLK_A                                                              \
  EVS(0, "q0") EVS(1, "q1") EVS(2, "q2") EVS(3, "q3") EVS(4, "q4")           \
  EVS(5, "q5") EVS(6, "q6") EVS(7, "q7") EVS(8, "q8") EVS(9, "q9")           \
  EVS(10, "q10") EVS(11, "q11") EVS(12, "q12") EVS(13, "q13") EVS(14, "q14") \
  EVS(15, "q15")

#define EVBLK_B                                                               \
  EVS(16, "q0") EVS(17, "q1") EVS(18, "q2") EVS(19, "q3") EVS(20, "q4")       \
  EVS(21, "q5") EVS(22, "q6") EVS(23, "q7") EVS(24, "q8") EVS(25, "q9")       \
  EVS(26, "q10") EVS(27, "q11") EVS(28, "q12") EVS(29, "q13") EVS(30, "q14")  \
  EVS(31, "q15")

__global__ __launch_bounds__(576, 1) void k_reduce(const u64* __restrict__ mask,
                                                   const float4* __restrict__ tb,
                                                   const float* __restrict__ sscore,
                                                   float* __restrict__ out) {
  int b = blockIdx.x;
  int tid = threadIdx.x;
  int w = tid >> 6, t = tid & 63;
  __shared__ u64 sbuf[2 * PROD * QROWS * 64];  // 128 KiB ring
  __shared__ u64 skeep[64];
  __shared__ u32 sbase[64];
  __shared__ int sdone, scnt;

  const u64* mb = mask + ((size_t)b * PRE) * 64;
  u64 remv = 0;   // (consumer) suppression bits for columns [64t,64t+64)
  u64 keepm = 0;  // (consumer) keep bits for rows [64t,64t+64)
  int cnt = 0;
  u32 sbufB = (u32)(uintptr_t)&sbuf[0];

#define LOADQ(buf_, qi_)                                                      \
  do {                                                                        \
    int qi__ = (qi_);                                                         \
    if (qi__ < NQ) {                                                          \
      const char* gsrc_ = (const char*)(mb + (size_t)qi__ * QROWS * 64);      \
      char* ldst_ =                                                           \
          (char*)sbuf + (size_t)(((buf_)*PROD + (w - 1)) * (QROWS * 64)) * 8; \
      _Pragma("unroll") for (int g_ = 0; g_ < 8; ++g_) {                      \
        __builtin_amdgcn_global_load_lds(                                     \
            (const __attribute__((address_space(1))) void*)(gsrc_ +           \
                                                            g_ * 1024 +      \
                                                            t * 16),          \
            (__attribute__((address_space(3))) void*)(ldst_ + g_ * 1024),     \
            16, 0, 0);                                                        \
      }                                                                       \
    }                                                                         \
  } while (0)

  if (w > 0) LOADQ(0, (w - 1));
  if (tid == 0) sdone = 0;
  __syncthreads();

  for (int r = 0; r < RND; ++r) {
    if (w > 0) {
      LOADQ((r + 1) & 1, (r + 1) * PROD + (w - 1));
    } else {
      int fin = 0;
      for (int k = 0; k < 4 && !fin; ++k) {
        int rb_ = r * 2 + (k >> 1);
        int bbhi = k & 1;
        u32 lb = sbufB + (u32)(((r & 1) * PROD + 2 * k) * (QROWS * 64) * 8) +
                 (u32)t * 8u;
        u64 w0, w1, w2, w3, w4, w5, w6, w7, w8, w9, w10, w11, w12, w13, w14,
            w15, w16, w17, w18, w19, w20, w21, w22, w23, w24, w25, w26, w27,
            w28, w29, w30, w31;
        asm volatile(
            "ds_read_b64 %0, %16 offset:0\n\t"
            "ds_read_b64 %1, %16 offset:512\n\t"
            "ds_read_b64 %2, %16 offset:1024\n\t"
            "ds_read_b64 %3, %16 offset:1536\n\t"
            "ds_read_b64 %4, %16 offset:2048\n\t"
            "ds_read_b64 %5, %16 offset:2560\n\t"
            "ds_read_b64 %6, %16 offset:3072\n\t"
            "ds_read_b64 %7, %16 offset:3584\n\t"
            "ds_read_b64 %8, %16 offset:4096\n\t"
            "ds_read_b64 %9, %16 offset:4608\n\t"
            "ds_read_b64 %10, %16 offset:5120\n\t"
            "ds_read_b64 %11, %16 offset:5632\n\t"
            "ds_read_b64 %12, %16 offset:6144\n\t"
            "ds_read_b64 %13, %16 offset:6656\n\t"
            "ds_read_b64 %14, %16 offset:7168\n\t"
            "ds_read_b64 %15, %16 offset:7680\n\t"
            : "=&v"(w0), "=&v"(w1), "=&v"(w2), "=&v"(w3), "=&v"(w4),
              "=&v"(w5), "=&v"(w6), "=&v"(w7), "=&v"(w8), "=&v"(w9),
              "=&v"(w10), "=&v"(w11), "=&v"(w12), "=&v"(w13), "=&v"(w14),
              "=&v"(w15)
            : "v"(lb));
        asm volatile(
            "ds_read_b64 %0, %16 offset:8192\n\t"
            "ds_read_b64 %1, %16 offset:8704\n\t"
            "ds_read_b64 %2, %16 offset:9216\n\t"
            "ds_read_b64 %3, %16 offset:9728\n\t"
            "ds_read_b64 %4, %16 offset:10240\n\t"
            "ds_read_b64 %5, %16 offset:10752\n\t"
            "ds_read_b64 %6, %16 offset:11264\n\t"
            "ds_read_b64 %7, %16 offset:11776\n\t"
            "ds_read_b64 %8, %16 offset:12288\n\t"
            "ds_read_b64 %9, %16 offset:12800\n\t"
            "ds_read_b64 %10, %16 offset:13312\n\t"
            "ds_read_b64 %11, %16 offset:13824\n\t"
            "ds_read_b64 %12, %16 offset:14336\n\t"
            "ds_read_b64 %13, %16 offset:14848\n\t"
            "ds_read_b64 %14, %16 offset:15360\n\t"
            "ds_read_b64 %15, %16 offset:15872\n\t"
            : "=&v"(w16), "=&v"(w17), "=&v"(w18), "=&v"(w19), "=&v"(w20),
              "=&v"(w21), "=&v"(w22), "=&v"(w23), "=&v"(w24), "=&v"(w25),
              "=&v"(w26), "=&v"(w27), "=&v"(w28), "=&v"(w29), "=&v"(w30),
              "=&v"(w31)
            : "v"(lb));
        asm volatile("s_waitcnt lgkmcnt(0)" ::: "memory");
        __builtin_amdgcn_sched_barrier(0);

        u32 a32, ev;
        if (!bbhi) {
          a32 = ~(u32)remv;
          asm volatile(EVBLK_A
                       : [a] "+v"(a32), [e] "=&v"(ev)
                       : [q0] "v"((u32)w0), [q1] "v"((u32)w1),
                         [q2] "v"((u32)w2), [q3] "v"((u32)w3),
                         [q4] "v"((u32)w4), [q5] "v"((u32)w5),
                         [q6] "v"((u32)w6), [q7] "v"((u32)w7),
                         [q8] "v"((u32)w8), [q9] "v"((u32)w9),
                         [q10] "v"((u32)w10), [q11] "v"((u32)w11),
                         [q12] "v"((u32)w12), [q13] "v"((u32)w13),
                         [q14] "v"((u32)w14), [q15] "v"((u32)w15));
          asm volatile(EVBLK_B
                       : [a] "+v"(a32), [e] "=&v"(ev)
                       : [q0] "v"((u32)w16), [q1] "v"((u32)w17),
                         [q2] "v"((u32)w18), [q3] "v"((u32)w19),
                         [q4] "v"((u32)w20), [q5] "v"((u32)w21),
                         [q6] "v"((u32)w22), [q7] "v"((u32)w23),
                         [q8] "v"((u32)w24), [q9] "v"((u32)w25),
                         [q10] "v"((u32)w26), [q11] "v"((u32)w27),
                         [q12] "v"((u32)w28), [q13] "v"((u32)w29),
                         [q14] "v"((u32)w30), [q15] "v"((u32)w31));
        } else {
          a32 = ~(u32)(remv >> 32);
          asm volatile(EVBLK_A
                       : [a] "+v"(a32), [e] "=&v"(ev)
                       : [q0] "v"((u32)(w0 >> 32)), [q1] "v"((u32)(w1 >> 32)),
                         [q2] "v"((u32)(w2 >> 32)), [q3] "v"((u32)(w3 >> 32)),
                         [q4] "v"((u32)(w4 >> 32)), [q5] "v"((u32)(w5 >> 32)),
                         [q6] "v"((u32)(w6 >> 32)), [q7] "v"((u32)(w7 >> 32)),
                         [q8] "v"((u32)(w8 >> 32)), [q9] "v"((u32)(w9 >> 32)),
                         [q10] "v"((u32)(w10 >> 32)),
                         [q11] "v"((u32)(w11 >> 32)),
                         [q12] "v"((u32)(w12 >> 32)),
                         [q13] "v"((u32)(w13 >> 32)),
                         [q14] "v"((u32)(w14 >> 32)),
                         [q15] "v"((u32)(w15 >> 32)));
          asm volatile(EVBLK_B
                       : [a] "+v"(a32), [e] "=&v"(ev)
                       : [q0] "v"((u32)(w16 >> 32)),
                         [q1] "v"((u32)(w17 >> 32)),
                         [q2] "v"((u32)(w18 >> 32)),
                         [q3] "v"((u32)(w19 >> 32)),
                         [q4] "v"((u32)(w20 >> 32)),
                         [q5] "v"((u32)(w21 >> 32)),
                         [q6] "v"((u32)(w22 >> 32)),
                         [q7] "v"((u32)(w23 >> 32)),
                         [q8] "v"((u32)(w24 >> 32)),
                         [q9] "v"((u32)(w25 >> 32)),
                         [q10] "v"((u32)(w26 >> 32)),
                         [q11] "v"((u32)(w27 >> 32)),
                         [q12] "v"((u32)(w28 >> 32)),
                         [q13] "v"((u32)(w29 >> 32)),
                         [q14] "v"((u32)(w30 >> 32)),
                         [q15] "v"((u32)(w31 >> 32)));
        }
        (void)ev;
        u32 kq = __builtin_amdgcn_readlane(a32, rb_);  // uniform keep bits

#define SELW(i, wi) ((((kq) >> (i)) & 1u) ? (wi) : 0ull)
        u64 o0 = SELW(0, w0) | SELW(1, w1) | SELW(2, w2) | SELW(3, w3) |
                 SELW(4, w4) | SELW(5, w5) | SELW(6, w6) | SELW(7, w7);
        u64 o1 = SELW(8, w8) | SELW(9, w9) | SELW(10, w10) | SELW(11, w11) |
                 SELW(12, w12) | SELW(13, w13) | SELW(14, w14) | SELW(15, w15);
        u64 o2 = SELW(16, w16) | SELW(17, w17) | SELW(18, w18) |
                 SELW(19, w19) | SELW(20, w20) | SELW(21, w21) |
                 SELW(22, w22) | SELW(23, w23);
        u64 o3 = SELW(24, w24) | SELW(25, w25) | SELW(26, w26) |
                 SELW(27, w27) | SELW(28, w28) | SELW(29, w29) |
                 SELW(30, w30) | SELW(31, w31);
#undef SELW
        remv |= (o0 | o1) | (o2 | o3);
        if (t == rb_) keepm |= (u64)kq << (bbhi ? 32 : 0);
        cnt += __popc(kq);
        if (cnt >= POST) fin = 1;
      }
      if (r == RND - 1) fin = 1;
      if (fin && t == 0) sdone = 1;
    }
    __syncthreads();
    if (sdone) break;
  }
#undef LOADQ

  // epilogue: publish keep bits + prefix, then all 576 threads write output
  if (w == 0) {
    skeep[t] = keepm;
    int nk = __popcll(keepm);
    int inc = nk;
#pragma unroll
    for (int off = 1; off < 64; off <<= 1) {
      int v = __shfl_up(inc, off);
      if (t >= off) inc += v;
    }
    sbase[t] = (u32)(inc - nk);
    if (t == 0) scnt = cnt < POST ? cnt : POST;
  }
  __syncthreads();
  int ntot = scnt;

  const float4* tbb = tb + (size_t)b * PRE;
  const float* ssb = sscore + (size_t)b * PRE;
  float4* outb = (float4*)out + (size_t)b * POST;
  float* outs = out + (size_t)B_ * POST * 4 + (size_t)b * POST;

  for (int i = tid; i < PRE; i += 576) {
    int wi = i >> 6, bi = i & 63;
    u64 km = skeep[wi];
    if ((km >> bi) & 1ull) {
      int rr = (int)sbase[wi] + __popcll(km & ((1ull << bi) - 1ull));
      if (rr < POST) {
        float4 v = tbb[i];
        float4 bx;
        bx.x = fminf(fmaxf(v.x, 0.f), 1.f);
        bx.y = fminf(fmaxf(v.y, 0.f), 1.f);
        bx.z = fminf(fmaxf(v.z, 0.f), 1.f);
        bx.w = fminf(fmaxf(v.w, 0.f), 1.f);
        outb[rr] = bx;
        outs[rr] = ssb[i];
      }
    }
  }
  for (int s2 = ntot + tid; s2 < POST; s2 += 576) {
    outb[s2] = make_float4(0.f, 0.f, 0.f, 0.f);
    outs[s2] = 0.f;
  }
}

extern "C" void kernel_launch(void* const* d_in, const int* in_sizes, int n_in,
                              void* d_out, int out_size, void* d_ws,
                              size_t ws_size, hipStream_t stream) {
  const float* boxes = (const float*)d_in[0];   // [16,200000,4]
  const float* scores = (const float*)d_in[1];  // [16,200000,1]
  float* out = (float*)d_out;

  char* ws = (char*)d_ws;
  size_t off = 0;
  auto alloc = [&](size_t bytes) {
    size_t o = off;
    off = (off + bytes + 255) & ~(size_t)255;
    return o;
  };
  // zero-initialized region first (one memset)
  size_t o_hist1 = alloc((size_t)B_ * 4096 * 4);
  size_t o_hist2 = alloc((size_t)B_ * 4096 * 4);
  size_t o_hist3 = alloc((size_t)B_ * 256 * 4);
  size_t o_pref = alloc(B_ * 4);
  size_t o_K = alloc(B_ * 4);
  size_t o_cgt = alloc((size_t)B_ * CNT_PAD * 4);
  size_t o_ceq = alloc((size_t)B_ * CNT_PAD * 4);
  size_t zbytes = off;
  // non-zeroed scratch
  size_t o_sel = alloc((size_t)B_ * PRE * 8);
  size_t o_eq = alloc((size_t)B_ * PRE * 4);
  size_t o_sscore = alloc((size_t)B_ * PRE * 4);
  size_t o_tb = alloc((size_t)B_ * PRE * 16);
  size_t o_mask = alloc((size_t)B_ * PRE * 64 * 8);
  if (off > ws_size) return;  // workspace too small -> visible failure

  u32* hist1 = (u32*)(ws + o_hist1);
  u32* hist2 = (u32*)(ws + o_hist2);
  u32* hist3 = (u32*)(ws + o_hist3);
  u32* pref = (u32*)(ws + o_pref);
  u32* K = (u32*)(ws + o_K);
  u32* cgt = (u32*)(ws + o_cgt);
  u32* ceq = (u32*)(ws + o_ceq);
  u64* sel = (u64*)(ws + o_sel);
  u32* eqbuf = (u32*)(ws + o_eq);
  float* sscore = (float*)(ws + o_sscore);
  float4* tb = (float4*)(ws + o_tb);
  u64* mask = (u64*)(ws + o_mask);

  hipMemsetAsync(d_ws, 0, zbytes, stream);

  dim3 scanGrid(128, B_);
  k_hist1<<<scanGrid, 256, 0, stream>>>(scores, hist1);
  k_thresh<<<B_, 64, 0, stream>>>(hist1, 4096, 20, pref, K);
  k_hist2<<<scanGrid, 256, 0, stream>>>(scores, pref, hist2);
  k_thresh<<<B_, 64, 0, stream>>>(hist2, 4096, 8, pref, K);
  k_hist3<<<scanGrid, 256, 0, stream>>>(scores, pref, hist3);
  k_thresh<<<B_, 64, 0, stream>>>(hist3, 256, 0, pref, K);
  k_select<<<scanGrid, 256, 0, stream>>>(scores, pref, cgt, ceq, sel, eqbuf);
  k_tie<<<B_, 256, 0, stream>>>(pref, K, ceq, eqbuf, sel);
  k_rank<<<dim3(PRE / 256, B_), 256, 0, stream>>>(sel, (const float4*)boxes,
                                                  tb, sscore);
  k_mask<<<dim3(2080, B_), 64, 0, stream>>>(tb, mask);
  k_reduce<<<B_, 576, 0, stream>>>(mask, tb, sscore, out);
}